// Round 1
// baseline (420.930 us; speedup 1.0000x reference)
//
#include <hip/hip_runtime.h>
#include <math.h>

// Problem constants (from reference):
// B=2048, C=1, H=W=128, TARGET_H=TARGET_W=70, SAVE=CUT=64, CX=CY=64.0
// Outputs (flat concat, fp32):
//   out0 target       : (2048,1,64,64)    = image*mask cropped [32:96,32:96]
//   out1 target_cut   : (2048,1,64,64)    = min(2*image,1) cropped [32:96,32:96]
//   out2 target_scene : (2048,1,128,128)  = image * (mask==0)
//   out3 target_raw   : (2048,1,128,128)  = image
//
// Mask is analytic: rotated-rectangle test per pixel, no gather needed.
// Numerics: fp32 ops via __f*_rn to match numpy op-for-op (no FMA contraction);
// per-image cos/sin computed in double then rounded -> correctly-rounded fp32.
//
// v2 changes (theory: kernel was ~205us @ ~2.3 TB/s, well under 6.3 TB/s ceiling):
//  - 4 float4 per thread, all loads issued before first use (4x MLP per lane)
//  - nontemporal loads/stores on every stream (write-allocate bypass; outputs
//    are never re-read, input is read exactly once)
//  - dropped the redundant clip (masked by `valid` in all cases -> bit-identical)

#define NB 2048

typedef float f32x4 __attribute__((ext_vector_type(4)));

__global__ __launch_bounds__(256) void kd_rotmask_kernel(
    const float* __restrict__ image,
    const float* __restrict__ azim,
    const float* __restrict__ alpha,
    float* __restrict__ out)
{
    const int b = blockIdx.y;                        // image index, uniform per block
    const int t = blockIdx.x * 256 + threadIdx.x;    // 0..1023 : base float4 index

    __shared__ float s_cs, s_sn, s_xd, s_xu, s_yd, s_yu;
    if (threadIdx.x == 0) {
        // a = deg2rad(-azimuth[b]) in fp32 exactly as numpy: (-az) * float32(pi/180)
        float a = __fmul_rn(-azim[b], 0.017453292519943295f);
        double ad = (double)a;
        s_cs = (float)cos(ad);   // correctly-rounded fp32 trig
        s_sn = (float)sin(ad);
        // x_up = round(CX + a0*35), round-half-even (jnp.round) == rintf
        s_xu = rintf(__fadd_rn(64.0f, __fmul_rn(alpha[0], 35.0f)));
        s_xd = rintf(__fsub_rn(64.0f, __fmul_rn(alpha[1], 35.0f)));
        s_yu = rintf(__fadd_rn(64.0f, __fmul_rn(alpha[2], 35.0f)));
        s_yd = rintf(__fsub_rn(64.0f, __fmul_rn(alpha[3], 35.0f)));
    }
    __syncthreads();
    const float cs = s_cs, sn = s_sn;
    const float xd = s_xd, xu = s_xu, yd = s_yd, yu = s_yu;

    const f32x4* img4 = (const f32x4*)image + (size_t)b * 4096;
    f32x4* out4 = (f32x4*)out;

    // Issue all 4 independent 16B loads up-front (64B/lane in flight).
    f32x4 v[4];
    #pragma unroll
    for (int k = 0; k < 4; ++k)
        v[k] = __builtin_nontemporal_load(img4 + t + k * 1024);

    #pragma unroll
    for (int k = 0; k < 4; ++k) {
        const int tid  = t + k * 1024;    // 0..4095 float4 index in image
        const int row  = tid >> 5;        // 0..127
        const int c4   = tid & 31;        // float4-chunk within row
        const int col0 = c4 << 2;         // first pixel column of this chunk

        const float Yf = (float)row - 63.5f;   // exact in fp32
        float tgt[4], scn[4];
        #pragma unroll
        for (int j = 0; j < 4; ++j) {
            const float Xf = (float)(col0 + j) - 63.5f;   // exact
            // xin = cos*X + sin*Y ; yin = (-sin)*X + cos*Y   (numpy op order, no fma)
            const float xin = __fadd_rn(__fmul_rn(cs, Xf), __fmul_rn(sn, Yf));
            const float yin = __fadd_rn(__fmul_rn(-sn, Xf), __fmul_rn(cs, Yf));
            const float colf = floorf(__fadd_rn(__fadd_rn(xin, 63.5f), 0.5f));
            const float rowf = floorf(__fadd_rn(__fadd_rn(yin, 63.5f), 0.5f));
            const bool valid = (colf >= 0.0f) && (colf < 128.0f) &&
                               (rowf >= 0.0f) && (rowf < 128.0f);
            // Reference clips then indexes, but !valid zeroes the result and
            // under `valid` the clip is the identity -> clip is redundant.
            const bool m = valid && (rowf >= xd) && (rowf < xu) &&
                                    (colf >= yd) && (colf < yu);
            const float p = v[k][j];
            tgt[j] = m ? p : 0.0f;   // image * mask
            scn[j] = m ? 0.0f : p;   // image * (mask==0)
        }

        // float4-unit offsets in concatenated output:
        //   out0 @ 0            (2048*1024 float4)
        //   out1 @ 2097152      (2048*1024)
        //   out2 @ 4194304      (2048*4096)
        //   out3 @ 12582912     (2048*4096)
        const size_t full_idx = (size_t)b * 4096 + tid;
        f32x4 s4 = { scn[0], scn[1], scn[2], scn[3] };
        __builtin_nontemporal_store(s4,   out4 + 4194304u  + full_idx);
        __builtin_nontemporal_store(v[k], out4 + 12582912u + full_idx);

        // crop region: rows 32..95, cols 32..95 -> c4 chunks 8..23 (16B aligned)
        if (row >= 32 && row < 96 && c4 >= 8 && c4 < 24) {
            const size_t ti = (size_t)b * 1024 + (size_t)(row - 32) * 16 + (c4 - 8);
            f32x4 t4 = { tgt[0], tgt[1], tgt[2], tgt[3] };
            __builtin_nontemporal_store(t4, out4 + ti);
            f32x4 c4v;
            #pragma unroll
            for (int j = 0; j < 4; ++j) {
                const float e = __fmul_rn(v[k][j], 2.0f);   // exact
                c4v[j] = (e >= 1.0f) ? 1.0f : e;            // image_eq
            }
            __builtin_nontemporal_store(c4v, out4 + 2097152u + ti);
        }
    }
}

extern "C" void kernel_launch(void* const* d_in, const int* in_sizes, int n_in,
                              void* d_out, int out_size, void* d_ws, size_t ws_size,
                              hipStream_t stream) {
    const float* image = (const float*)d_in[0];
    const float* azim  = (const float*)d_in[1];
    const float* alpha = (const float*)d_in[2];
    float* out = (float*)d_out;

    dim3 grid(4, NB);   // 4 blocks x 256 threads x 4 float4 = 4096 float4 / image
    dim3 block(256);
    hipLaunchKernelGGL(kd_rotmask_kernel, grid, block, 0, stream,
                       image, azim, alpha, out);
}

// Round 4
// 420.401 us; speedup vs baseline: 1.0013x; 1.0013x over previous
//
#include <hip/hip_runtime.h>
#include <math.h>

// Problem constants (from reference):
// B=2048, C=1, H=W=128, TARGET_H=TARGET_W=70, SAVE=CUT=64, CX=CY=64.0
// Outputs (flat concat, fp32):
//   out0 target       : (2048,1,64,64)    = image*mask cropped [32:96,32:96]
//   out1 target_cut   : (2048,1,64,64)    = min(2*image,1) cropped [32:96,32:96]
//   out2 target_scene : (2048,1,128,128)  = image * (mask==0)
//   out3 target_raw   : (2048,1,128,128)  = image
//
// Mask is analytic: rotated-rectangle test per pixel, no gather needed.
// Numerics: fp32 ops via __f*_rn to match numpy op-for-op (no FMA contraction);
// per-image cos/sin computed in double then rounded -> correctly-rounded fp32.
//
// v3: each thread's 4 chunks are rows {r0, r0+32, r0+64, r0+96} with the same
// column chunk c4 -> crop rows [32,96) are EXACTLY k=1 and k=2 (compile-time),
// and the crop predicate reduces to a single column test. Stores are regular
// (non-nt: fill kernel hits 6.4 TB/s without nt; v2's nt stores were neutral
// at best); input loads stay nontemporal (read exactly once, keep L2 for
// the store streams).
//
// (Rounds 2-3 were infra failures — container acquisition; identical resubmit.
//  Addressing re-audited: all reads/writes in-bounds, no harness tripwires.)

#define NB 2048

typedef float f32x4 __attribute__((ext_vector_type(4)));

__global__ __launch_bounds__(256) void kd_rotmask_kernel(
    const float* __restrict__ image,
    const float* __restrict__ azim,
    const float* __restrict__ alpha,
    float* __restrict__ out)
{
    const int b = blockIdx.y;                        // image index, uniform per block
    const int t = blockIdx.x * 256 + threadIdx.x;    // 0..1023 : base float4 index

    __shared__ float s_cs, s_sn, s_xd, s_xu, s_yd, s_yu;
    if (threadIdx.x == 0) {
        // a = deg2rad(-azimuth[b]) in fp32 exactly as numpy: (-az) * float32(pi/180)
        float a = __fmul_rn(-azim[b], 0.017453292519943295f);
        double ad = (double)a;
        s_cs = (float)cos(ad);   // correctly-rounded fp32 trig
        s_sn = (float)sin(ad);
        // x_up = round(CX + a0*35), round-half-even (jnp.round) == rintf
        s_xu = rintf(__fadd_rn(64.0f, __fmul_rn(alpha[0], 35.0f)));
        s_xd = rintf(__fsub_rn(64.0f, __fmul_rn(alpha[1], 35.0f)));
        s_yu = rintf(__fadd_rn(64.0f, __fmul_rn(alpha[2], 35.0f)));
        s_yd = rintf(__fsub_rn(64.0f, __fmul_rn(alpha[3], 35.0f)));
    }
    __syncthreads();
    const float cs = s_cs, sn = s_sn;
    const float xd = s_xd, xu = s_xu, yd = s_yd, yu = s_yu;

    const int r0   = t >> 5;        // 0..31 : row of k=0 chunk
    const int c4   = t & 31;        // float4-chunk within row (same for all k)
    const int col0 = c4 << 2;       // first pixel column of this chunk

    const f32x4* img4 = (const f32x4*)image + (size_t)b * 4096 + t;

    // Issue all 4 independent 16B loads up-front (64B/lane in flight).
    f32x4 v[4];
    #pragma unroll
    for (int k = 0; k < 4; ++k)
        v[k] = __builtin_nontemporal_load(img4 + k * 1024);

    f32x4* out4 = (f32x4*)out;
    const size_t base_full = (size_t)b * 4096 + t;
    const bool crop_col = (c4 >= 8) && (c4 < 24);   // cols 32..95, 16B-aligned

    #pragma unroll
    for (int k = 0; k < 4; ++k) {
        const int row = r0 + (k << 5);          // r0 + 32k, exact
        const float Yf = (float)row - 63.5f;    // exact in fp32
        f32x4 tgt, scn;
        #pragma unroll
        for (int j = 0; j < 4; ++j) {
            const float Xf = (float)(col0 + j) - 63.5f;   // exact
            // xin = cos*X + sin*Y ; yin = (-sin)*X + cos*Y   (numpy op order, no fma)
            const float xin = __fadd_rn(__fmul_rn(cs, Xf), __fmul_rn(sn, Yf));
            const float yin = __fadd_rn(__fmul_rn(-sn, Xf), __fmul_rn(cs, Yf));
            const float colf = floorf(__fadd_rn(__fadd_rn(xin, 63.5f), 0.5f));
            const float rowf = floorf(__fadd_rn(__fadd_rn(yin, 63.5f), 0.5f));
            const bool valid = (colf >= 0.0f) && (colf < 128.0f) &&
                               (rowf >= 0.0f) && (rowf < 128.0f);
            // Reference clips then indexes, but !valid zeroes the result and
            // under `valid` the clip is the identity -> clip is redundant.
            const bool m = valid && (rowf >= xd) && (rowf < xu) &&
                                    (colf >= yd) && (colf < yu);
            const float p = v[k][j];
            tgt[j] = m ? p : 0.0f;   // image * mask
            scn[j] = m ? 0.0f : p;   // image * (mask==0)
        }

        // float4-unit offsets in concatenated output:
        //   out0 @ 0            (2048*1024 float4)
        //   out1 @ 2097152      (2048*1024)
        //   out2 @ 4194304      (2048*4096)
        //   out3 @ 12582912     (2048*4096)
        const size_t fi = base_full + (size_t)(k << 10);
        out4[4194304u  + fi] = scn;
        out4[12582912u + fi] = v[k];

        // crop rows [32,96) are exactly k==1 (rows 32..63) and k==2 (rows 64..95)
        if ((k == 1 || k == 2) && crop_col) {
            const int row_out = r0 + ((k - 1) << 5);   // 0..63
            const size_t ti = (size_t)b * 1024 + (size_t)row_out * 16 + (c4 - 8);
            out4[ti] = tgt;
            f32x4 cut;
            #pragma unroll
            for (int j = 0; j < 4; ++j) {
                const float e = __fmul_rn(v[k][j], 2.0f);   // exact
                cut[j] = (e >= 1.0f) ? 1.0f : e;            // image_eq
            }
            out4[2097152u + ti] = cut;
        }
    }
}

extern "C" void kernel_launch(void* const* d_in, const int* in_sizes, int n_in,
                              void* d_out, int out_size, void* d_ws, size_t ws_size,
                              hipStream_t stream) {
    const float* image = (const float*)d_in[0];
    const float* azim  = (const float*)d_in[1];
    const float* alpha = (const float*)d_in[2];
    float* out = (float*)d_out;

    dim3 grid(4, NB);   // 4 blocks x 256 threads x 4 float4 = 4096 float4 / image
    dim3 block(256);
    hipLaunchKernelGGL(kd_rotmask_kernel, grid, block, 0, stream,
                       image, azim, alpha, out);
}